// Round 10
// baseline (189.689 us; speedup 1.0000x reference)
//
#include <hip/hip_runtime.h>

// Round 18: fuse attn_reduce into attn (split-k last-block fixup).
//  - attn: unchanged r15 k-loop (zero-LDS/zero-barrier, T12 in-register
//    softmax, 142.9 us best). After partial stores: __syncthreads ->
//    tid0 {threadfence (release) + atomicAdd(cnt[b*32+qt])}; the last
//    arriving half-block does the 4-way reduction + final out write
//    (threadfence acquire first -- cross-XCD visibility per G16).
//  - prep_wt zeros the 128 counters (visible to attn via kernel-boundary
//    release). attn_reduce kernel deleted -> one fewer dispatch + gap.
//  - proj: r13 fused QKV. prep otherwise unchanged.

typedef __bf16 bf16;
typedef __bf16 bf16x4 __attribute__((ext_vector_type(4)));
typedef __bf16 bf16x8 __attribute__((ext_vector_type(8)));
typedef float  f32x16 __attribute__((ext_vector_type(16)));

#define MFMA(a, b, c) __builtin_amdgcn_mfma_f32_32x32x16_bf16(a, b, c, 0, 0, 0)

constexpr int T = 4096, D = 1024, HS = 64;
constexpr int ROWS = 4 * T;                   // 16384
constexpr float QSCL = 0.045084220027797f;    // (1/32) * log2(e)

__device__ __forceinline__ void gld16(const void* g, void* l) {
    __builtin_amdgcn_global_load_lds(
        (const __attribute__((address_space(1))) unsigned int*)g,
        (__attribute__((address_space(3))) unsigned int*)l, 16, 0, 0);
}

__device__ inline f32x16 zero16() {
    f32x16 z;
#pragma unroll
    for (int i = 0; i < 16; ++i) z[i] = 0.f;
    return z;
}

// ---- prep: Wt[192][1024] bf16 = concat(Wq^T*QSCL, Wk^T, Wv^T); zero cnt ----
__global__ __launch_bounds__(256) void prep_wt(
    const float* __restrict__ Wq, const float* __restrict__ Wk,
    const float* __restrict__ Wv, bf16* __restrict__ Wt,
    unsigned* __restrict__ cnt)
{
    __shared__ float Xf[64 * 68];
    if (blockIdx.x == 0 && threadIdx.x < 128) cnt[threadIdx.x] = 0u;
    const int m = blockIdx.x >> 4, dt = blockIdx.x & 15;
    const float* W = (m == 0) ? Wq : ((m == 1) ? Wk : Wv);
    const int d0 = dt * 64;
#pragma unroll
    for (int j = 0; j < 4; ++j) {
        int i = threadIdx.x + 256 * j;
        int dr = i >> 4, c4 = i & 15;
        float4 v = *(const float4*)(W + (size_t)(d0 + dr) * 64 + c4 * 4);
        *(float4*)&Xf[dr * 68 + c4 * 4] = v;
    }
    __syncthreads();
    const float scl = (m == 0) ? QSCL : 1.0f;
#pragma unroll
    for (int j = 0; j < 4; ++j) {
        int o = threadIdx.x + 256 * j;
        int h = o >> 4, dc = o & 15;
        bf16x4 w;
#pragma unroll
        for (int k = 0; k < 4; ++k) w[k] = (bf16)(Xf[(dc * 4 + k) * 68 + h] * scl);
        *(bf16x4*)(Wt + (size_t)(m * 64 + h) * D + d0 + dc * 4) = w;
    }
}

// ---- fused projection: grid 256 = 8 xcd x 32 mtile; Q+K+V per block ----
__global__ __launch_bounds__(256) void qkv_proj(
    const float* __restrict__ x, const bf16* __restrict__ Wt,
    bf16* __restrict__ Qg, bf16* __restrict__ Kgt, bf16* __restrict__ Vgt)
{
    __shared__ __align__(16) bf16  Xb[2][64 * 64];   // swizzled granule: [r][u^(r&7)]
    __shared__ __align__(16) short Ws[2][192 * 64];  // swizzled: [h][u^(h&7)]
    const int tid = threadIdx.x;
    const int w = tid >> 6, lane = tid & 63, ln5 = lane & 31, hi = lane >> 5;
    const int tt = w & 1, hh = w >> 1;
    const int xcd = blockIdx.x & 7, mlocal = blockIdx.x >> 3;
    const int r0 = (xcd * 32 + mlocal) * 64;
    const int wb = tid & 448;

    auto stageW = [&](int kc, int buf) {
#pragma unroll
        for (int k2 = 0; k2 < 6; ++k2) {
            int s = k2 * 256 + tid;
            int h = s >> 3, j = s & 7, u = j ^ (h & 7);
            gld16(Wt + (size_t)h * D + kc * 64 + u * 8,
                  &Ws[buf][(k2 * 256 + wb) * 8]);
        }
    };
    float4 xra[2], xrb[2];
    auto stageX_load = [&](int kc) {
#pragma unroll
        for (int k = 0; k < 2; ++k) {
            int e = k * 256 + tid;
            int r = e >> 3, d0 = (e & 7) * 8;
            const float* src = x + (size_t)(r0 + r) * D + kc * 64 + d0;
            xra[k] = *(const float4*)src;
            xrb[k] = *(const float4*)(src + 4);
        }
    };
    auto stageX_write = [&](int buf) {
#pragma unroll
        for (int k = 0; k < 2; ++k) {
            int e = k * 256 + tid;
            int r = e >> 3, d0 = (e & 7) * 8;
            bf16x8 v;
            v[0] = (bf16)xra[k].x; v[1] = (bf16)xra[k].y;
            v[2] = (bf16)xra[k].z; v[3] = (bf16)xra[k].w;
            v[4] = (bf16)xrb[k].x; v[5] = (bf16)xrb[k].y;
            v[6] = (bf16)xrb[k].z; v[7] = (bf16)xrb[k].w;
            *(bf16x8*)&Xb[buf][r * 64 + (((d0 >> 3) ^ (r & 7)) * 8)] = v;
        }
    };

    f32x16 acc0 = zero16(), acc1 = zero16(), acc2 = zero16();
    const int rx = tt * 32 + ln5;
    const int hq = hh * 32 + ln5;
    const int swz = ln5 & 7;

    stageX_load(0); stageW(0, 0); stageX_write(0);
    __syncthreads();
    for (int kc = 0; kc < 16; ++kc) {
        const int cur = kc & 1;
        if (kc < 15) { stageW(kc + 1, cur ^ 1); stageX_load(kc + 1); }
        const bf16*  Xc = &Xb[cur][0];
        const short* Wb = &Ws[cur][0];
#pragma unroll
        for (int ks = 0; ks < 4; ++ks) {
            int g = (ks * 2 + hi) ^ swz;
            bf16x8 fx = *(const bf16x8*)&Xc[rx * 64 + g * 8];
            bf16x8 w0 = *(const bf16x8*)&Wb[(hq)       * 64 + g * 8];
            bf16x8 w1 = *(const bf16x8*)&Wb[(64 + hq)  * 64 + g * 8];
            bf16x8 w2 = *(const bf16x8*)&Wb[(128 + hq) * 64 + g * 8];
            acc0 = MFMA(w0, fx, acc0);   // Q: C^T (col = t)
            acc1 = MFMA(w1, fx, acc1);   // K: C^T (col = t)
            acc2 = MFMA(fx, w2, acc2);   // V: C   (col = h)
        }
        if (kc < 15) stageX_write(cur ^ 1);
        __syncthreads();
    }

    {
        int t = r0 + tt * 32 + ln5;
#pragma unroll
        for (int g = 0; g < 4; ++g) {
            int h0 = hh * 32 + 8 * g + 4 * hi;
            bf16x4 v;
#pragma unroll
            for (int k = 0; k < 4; ++k) v[k] = (bf16)acc0[4 * g + k];
            *(bf16x4*)(Qg + (size_t)t * HS + h0) = v;
        }
    }
    {
        int t = r0 + tt * 32 + ln5;
#pragma unroll
        for (int g = 0; g < 4; ++g) {
            int h0 = hh * 32 + 8 * g + 4 * hi;
            bf16x4 v;
#pragma unroll
            for (int k = 0; k < 4; ++k) v[k] = (bf16)acc1[4 * g + k];
            int j = (h0 >> 3) ^ (t & 7);
            *(bf16x4*)(Kgt + (size_t)t * HS + j * 8 + 4 * hi) = v;
        }
    }
    {
        int hr = hh * 32 + ln5;
#pragma unroll
        for (int g = 0; g < 4; ++g) {
            int t0 = tt * 32 + 8 * g + 4 * hi;
            bf16x4 v;
#pragma unroll
            for (int k = 0; k < 4; ++k) v[k] = (bf16)acc2[4 * g + k];
            int j = (t0 >> 3) ^ (hr & 7);
            *(bf16x4*)(Vgt + (size_t)r0 * HS + hr * 64 + j * 8 + 4 * hi) = v;
        }
    }
}

// ---- attention: block = 128 q-rows; wave = 64 q-cols x 32-kr half-chunk ----
// Zero-LDS/zero-barrier k-loop (r15); fused split-k reduction epilogue.
__global__ __launch_bounds__(256, 2) void attn(
    const bf16* __restrict__ Qg, const bf16* __restrict__ Kgt,
    const bf16* __restrict__ Vgt, float* __restrict__ Op,
    float* __restrict__ Lp, float* __restrict__ out,
    unsigned* __restrict__ cnt, int split)
{
    __shared__ __align__(16) short PO[16384];        // 32 KB: epilogue Ox overlay
    __shared__ float Lx[128];
    __shared__ int lastf;

    const int tid = threadIdx.x;
    const int w = tid >> 6, lane = tid & 63, ln5 = lane & 31, hi = lane >> 5;
    const int wq = w & 1, wk = w >> 1;

    int b, qt, half;
    if (split == 4) {
        int rest = blockIdx.x >> 3; qt = rest & 31;
        int combo = (blockIdx.x & 7) + 8 * (rest >> 5);   // (b,half) pinned per XCD
        b = combo >> 2; half = combo & 3;
    } else if (split == 2) {
        int c2 = blockIdx.x & 7; b = c2 >> 1; half = c2 & 1; qt = blockIdx.x >> 3;
    } else { b = blockIdx.x & 3; half = 0; qt = blockIdx.x >> 2; }

    const int rbase = b * T;
    const int seg = T / split;
    const int kb0 = rbase + half * seg;
    const int nc = seg / 64;
    const int qrow0 = rbase + qt * 128 + wq * 64;

    bf16x8 bq[2][4];
    {
        const bf16* qp = Qg + (size_t)(qrow0 + ln5) * HS + hi * 8;
#pragma unroll
        for (int qs = 0; qs < 2; ++qs)
#pragma unroll
            for (int ks = 0; ks < 4; ++ks)
                bq[qs][ks] = *(const bf16x8*)(qp + (size_t)qs * 32 * HS + ks * 16);
    }

    const bf16* Kc = Kgt + (size_t)kb0 * HS;
    const bf16* Vc = Vgt + (size_t)kb0 * HS;

    f32x16 O00 = zero16(), O01 = zero16(), O10 = zero16(), O11 = zero16();
    float l0 = 0.f, l1 = 0.f;
    const int swz = ln5 & 7;
    const int krow = (wk * 32 + ln5) * 64;           // K frag row (shorts)
    const int ko0 = krow + ((0 + hi) ^ swz) * 8;
    const int ko1 = krow + ((2 + hi) ^ swz) * 8;
    const int ko2 = krow + ((4 + hi) ^ swz) * 8;
    const int ko3 = krow + ((6 + hi) ^ swz) * 8;
    const int ku0 = ((wk * 4 + 0 + hi) ^ swz) * 8;   // PV ks=0
    const int ku1 = ((wk * 4 + 2 + hi) ^ swz) * 8;   // PV ks=1
    const int vr0 = ln5 * 64, vr1 = (32 + ln5) * 64;

    bf16x8 kf0 = *(const bf16x8*)(Kc + ko0);
    bf16x8 kf1 = *(const bf16x8*)(Kc + ko1);
    bf16x8 kf2 = *(const bf16x8*)(Kc + ko2);
    bf16x8 kf3 = *(const bf16x8*)(Kc + ko3);

    union U8 { unsigned u[4]; bf16x8 v; };

    for (int c = 0; c < nc; ++c) {
        const bf16* Vb = Vc + (size_t)c * 4096;
        bf16x8 v00 = *(const bf16x8*)(Vb + vr0 + ku0);
        bf16x8 v01 = *(const bf16x8*)(Vb + vr0 + ku1);
        bf16x8 v10 = *(const bf16x8*)(Vb + vr1 + ku0);
        bf16x8 v11 = *(const bf16x8*)(Vb + vr1 + ku1);
        const bool pf = (c + 1 < nc);
        bf16x8 kn0, kn1, kn2, kn3;
        if (pf) {
            const bf16* Kn = Kc + (size_t)(c + 1) * 4096;
            kn0 = *(const bf16x8*)(Kn + ko0);
            kn1 = *(const bf16x8*)(Kn + ko1);
            kn2 = *(const bf16x8*)(Kn + ko2);
            kn3 = *(const bf16x8*)(Kn + ko3);
        }

        // S^T = K_slice * Q^T  (32 kr x 64 q)
        f32x16 S0 = zero16(), S1 = zero16();
        S0 = MFMA(kf0, bq[0][0], S0); S1 = MFMA(kf0, bq[1][0], S1);
        S0 = MFMA(kf1, bq[0][1], S0); S1 = MFMA(kf1, bq[1][1], S1);
        S0 = MFMA(kf2, bq[0][2], S0); S1 = MFMA(kf2, bq[1][2], S1);
        S0 = MFMA(kf3, bq[0][3], S0); S1 = MFMA(kf3, bq[1][3], S1);

        // no-max softmax; pack P^T to bf16 in-register (T12)
        unsigned wa[8], wbq[8];
#pragma unroll
        for (int g = 0; g < 4; ++g) {
            float p0 = __builtin_amdgcn_exp2f(S0[4 * g + 0]);
            float p1 = __builtin_amdgcn_exp2f(S0[4 * g + 1]);
            float p2 = __builtin_amdgcn_exp2f(S0[4 * g + 2]);
            float p3 = __builtin_amdgcn_exp2f(S0[4 * g + 3]);
            l0 += (p0 + p1) + (p2 + p3);
            asm("v_cvt_pk_bf16_f32 %0, %1, %2" : "=v"(wa[2 * g])     : "v"(p0), "v"(p1));
            asm("v_cvt_pk_bf16_f32 %0, %1, %2" : "=v"(wa[2 * g + 1]) : "v"(p2), "v"(p3));
        }
#pragma unroll
        for (int g = 0; g < 4; ++g) {
            float p0 = __builtin_amdgcn_exp2f(S1[4 * g + 0]);
            float p1 = __builtin_amdgcn_exp2f(S1[4 * g + 1]);
            float p2 = __builtin_amdgcn_exp2f(S1[4 * g + 2]);
            float p3 = __builtin_amdgcn_exp2f(S1[4 * g + 3]);
            l1 += (p0 + p1) + (p2 + p3);
            asm("v_cvt_pk_bf16_f32 %0, %1, %2" : "=v"(wbq[2 * g])     : "v"(p0), "v"(p1));
            asm("v_cvt_pk_bf16_f32 %0, %1, %2" : "=v"(wbq[2 * g + 1]) : "v"(p2), "v"(p3));
        }
#pragma unroll
        for (int j = 0; j < 2; ++j) {
            asm("v_permlane32_swap_b32 %0, %1" : "+v"(wa[j]),      "+v"(wa[j + 2]));
            asm("v_permlane32_swap_b32 %0, %1" : "+v"(wa[4 + j]),  "+v"(wa[6 + j]));
            asm("v_permlane32_swap_b32 %0, %1" : "+v"(wbq[j]),     "+v"(wbq[j + 2]));
            asm("v_permlane32_swap_b32 %0, %1" : "+v"(wbq[4 + j]), "+v"(wbq[6 + j]));
        }
        U8 fa0, fa1, fb0, fb1;
        fa0.u[0] = wa[0];  fa0.u[1] = wa[1];  fa0.u[2] = wa[2];  fa0.u[3] = wa[3];
        fa1.u[0] = wa[4];  fa1.u[1] = wa[5];  fa1.u[2] = wa[6];  fa1.u[3] = wa[7];
        fb0.u[0] = wbq[0]; fb0.u[1] = wbq[1]; fb0.u[2] = wbq[2]; fb0.u[3] = wbq[3];
        fb1.u[0] = wbq[4]; fb1.u[1] = wbq[5]; fb1.u[2] = wbq[6]; fb1.u[3] = wbq[7];

        // O^T += V^T_slice * P^T  (all operands in registers)
        O00 = MFMA(v00, fa0.v, O00);
        O01 = MFMA(v00, fb0.v, O01);
        O10 = MFMA(v10, fa0.v, O10);
        O11 = MFMA(v10, fb0.v, O11);
        O00 = MFMA(v01, fa1.v, O00);
        O01 = MFMA(v01, fb1.v, O01);
        O10 = MFMA(v11, fa1.v, O10);
        O11 = MFMA(v11, fb1.v, O11);

        if (pf) { kf0 = kn0; kf1 = kn1; kf2 = kn2; kf3 = kn3; }
    }

    l0 += __shfl_xor(l0, 32, 64);
    l1 += __shfl_xor(l1, 32, 64);

    // wk-combine through the 32 KB Ox overlay
    __syncthreads();
    float* Ox = (float*)&PO[0];                      // [wq][h 64][q 64]
    if (wk == 1) {
#pragma unroll
        for (int g = 0; g < 4; ++g)
#pragma unroll
            for (int k = 0; k < 4; ++k) {
                int h0 = 8 * g + 4 * hi + k;
                Ox[wq * 4096 + h0 * 64 + ln5]             = O00[4 * g + k];
                Ox[wq * 4096 + h0 * 64 + 32 + ln5]        = O01[4 * g + k];
                Ox[wq * 4096 + (32 + h0) * 64 + ln5]      = O10[4 * g + k];
                Ox[wq * 4096 + (32 + h0) * 64 + 32 + ln5] = O11[4 * g + k];
            }
        if (hi == 0) { Lx[wq * 64 + ln5] = l0; Lx[wq * 64 + 32 + ln5] = l1; }
    }
    __syncthreads();
    if (wk == 0) {
#pragma unroll
        for (int g = 0; g < 4; ++g)
#pragma unroll
            for (int k = 0; k < 4; ++k) {
                int h0 = 8 * g + 4 * hi + k;
                O00[4 * g + k] += Ox[wq * 4096 + h0 * 64 + ln5];
                O01[4 * g + k] += Ox[wq * 4096 + h0 * 64 + 32 + ln5];
                O10[4 * g + k] += Ox[wq * 4096 + (32 + h0) * 64 + ln5];
                O11[4 * g + k] += Ox[wq * 4096 + (32 + h0) * 64 + 32 + ln5];
            }
        l0 += Lx[wq * 64 + ln5];
        l1 += Lx[wq * 64 + 32 + ln5];

        int q0 = qrow0 + ln5, q1 = qrow0 + 32 + ln5;
        if (split == 1) {
            float i0 = 1.0f / l0, i1 = 1.0f / l1;
#pragma unroll
            for (int g = 0; g < 4; ++g) {
                int h0 = 8 * g + 4 * hi;
                float4 o;
                o.x = O00[4*g+0]*i0; o.y = O00[4*g+1]*i0; o.z = O00[4*g+2]*i0; o.w = O00[4*g+3]*i0;
                *(float4*)(out + (size_t)q0 * HS + h0) = o;
                o.x = O01[4*g+0]*i1; o.y = O01[4*g+1]*i1; o.z = O01[4*g+2]*i1; o.w = O01[4*g+3]*i1;
                *(float4*)(out + (size_t)q1 * HS + h0) = o;
                o.x = O10[4*g+0]*i0; o.y = O10[4*g+1]*i0; o.z = O10[4*g+2]*i0; o.w = O10[4*g+3]*i0;
                *(float4*)(out + (size_t)q0 * HS + 32 + h0) = o;
                o.x = O11[4*g+0]*i1; o.y = O11[4*g+1]*i1; o.z = O11[4*g+2]*i1; o.w = O11[4*g+3]*i1;
                *(float4*)(out + (size_t)q1 * HS + 32 + h0) = o;
            }
        } else {
            float* Od = Op + (size_t)half * ROWS * HS;
#pragma unroll
            for (int g = 0; g < 4; ++g) {
                int h0 = 8 * g + 4 * hi;
                float4 o;
                o.x = O00[4*g+0]; o.y = O00[4*g+1]; o.z = O00[4*g+2]; o.w = O00[4*g+3];
                *(float4*)(Od + (size_t)q0 * HS + h0) = o;
                o.x = O01[4*g+0]; o.y = O01[4*g+1]; o.z = O01[4*g+2]; o.w = O01[4*g+3];
                *(float4*)(Od + (size_t)q1 * HS + h0) = o;
                o.x = O10[4*g+0]; o.y = O10[4*g+1]; o.z = O10[4*g+2]; o.w = O10[4*g+3];
                *(float4*)(Od + (size_t)q0 * HS + 32 + h0) = o;
                o.x = O11[4*g+0]; o.y = O11[4*g+1]; o.z = O11[4*g+2]; o.w = O11[4*g+3];
                *(float4*)(Od + (size_t)q1 * HS + 32 + h0) = o;
            }
            if (hi == 0) {
                Lp[half * ROWS + q0] = l0;
                Lp[half * ROWS + q1] = l1;
            }
        }
    }

    // ---- fused split-k completion: last half-block reduces (b,qt) ----
    if (split > 1) {
        __syncthreads();                              // all partial stores done
        if (tid == 0) {
            __threadfence();                          // release: L2 writeback
            lastf = (atomicAdd(&cnt[b * 32 + qt], 1u) == (unsigned)(split - 1));
        }
        __syncthreads();
        if (lastf) {
            __threadfence();                          // acquire: drop stale lines
            const int row0 = rbase + qt * 128;
            for (int i = tid; i < 128 * 16; i += 256) {
                size_t q = (size_t)(row0 + (i >> 4));
                int col4 = (i & 15) * 4;
                float4 s; s.x = s.y = s.z = s.w = 0.f;
                float lsum = 0.f;
                for (int h = 0; h < split; ++h) {
                    float4 a = *(const float4*)(Op + ((size_t)h * ROWS + q) * HS + col4);
                    s.x += a.x; s.y += a.y; s.z += a.z; s.w += a.w;
                    lsum += Lp[h * ROWS + q];
                }
                float inv = 1.0f / lsum;
                s.x *= inv; s.y *= inv; s.z *= inv; s.w *= inv;
                *(float4*)(out + q * HS + col4) = s;
            }
        }
    }
}

extern "C" void kernel_launch(void* const* d_in, const int* in_sizes, int n_in,
                              void* d_out, int out_size, void* d_ws, size_t ws_size,
                              hipStream_t stream)
{
    const float* x  = (const float*)d_in[0];
    const float* Wq = (const float*)d_in[1];
    const float* Wk = (const float*)d_in[2];
    const float* Wv = (const float*)d_in[3];
    float* out = (float*)d_out;

    char* ws = (char*)d_ws;
    bf16* Qg  = (bf16*)(ws);                          // 2 MB  [16384][64]
    bf16* Kgt = (bf16*)(ws + ((size_t)2 << 20));      // 2 MB  tiled+swizzled
    bf16* Vgt = (bf16*)(ws + ((size_t)4 << 20));      // 2 MB  tiled+swizzled
    bf16* Wt  = (bf16*)(ws + ((size_t)6 << 20));      // 384 KB [192][1024]
    float* Lp = (float*)(ws + ((size_t)6 << 20));     // 256 KB (overlays Wt; dead after proj)
    unsigned* cnt = (unsigned*)(ws + ((size_t)6 << 20) + ((size_t)448 << 10));  // 512 B
    float* Op = (float*)(ws + ((size_t)6 << 20) + ((size_t)1 << 19));

    const size_t base = ((size_t)6 << 20) + ((size_t)1 << 19);
    int split = 1;
    if (ws_size >= base + (size_t)4 * ROWS * HS * sizeof(float)) split = 4;
    else if (ws_size >= base + (size_t)2 * ROWS * HS * sizeof(float)) split = 2;

    prep_wt<<<48, 256, 0, stream>>>(Wq, Wk, Wv, Wt, cnt);
    qkv_proj<<<256, 256, 0, stream>>>(x, Wt, Qg, Kgt, Vgt);
    attn<<<128 * split, 256, 0, stream>>>(Qg, Kgt, Vgt, Op, Lp, out, cnt, split);
}

// Round 12
// 142.777 us; speedup vs baseline: 1.3286x; 1.3286x over previous
//
#include <hip/hip_runtime.h>

// Round 20: restore verified r15 base (142.9 us, split=4) + T5 setprio.
//  - r19's split=8 FAILED correctness (absmax 7.4e-3, unexplained) ->
//    split=8 quarantined; this round re-anchors the verified kernel.
//  - Only change vs r15: __builtin_amdgcn_s_setprio(1/0) around the QK and
//    PV MFMA clusters in attn (T5). Pure scheduler hint -- cannot change
//    values. Regime: attn's barrier-free waves progress independently
//    (the +4-7% attn case, m191), unlike lockstep proj (null, m190).
//  - proj: r13 fused QKV. prep/reduce unchanged.

typedef __bf16 bf16;
typedef __bf16 bf16x4 __attribute__((ext_vector_type(4)));
typedef __bf16 bf16x8 __attribute__((ext_vector_type(8)));
typedef float  f32x16 __attribute__((ext_vector_type(16)));

#define MFMA(a, b, c) __builtin_amdgcn_mfma_f32_32x32x16_bf16(a, b, c, 0, 0, 0)

constexpr int T = 4096, D = 1024, HS = 64;
constexpr int ROWS = 4 * T;                   // 16384
constexpr float QSCL = 0.045084220027797f;    // (1/32) * log2(e)

__device__ __forceinline__ void gld16(const void* g, void* l) {
    __builtin_amdgcn_global_load_lds(
        (const __attribute__((address_space(1))) unsigned int*)g,
        (__attribute__((address_space(3))) unsigned int*)l, 16, 0, 0);
}

__device__ inline f32x16 zero16() {
    f32x16 z;
#pragma unroll
    for (int i = 0; i < 16; ++i) z[i] = 0.f;
    return z;
}

// ---- prep: Wt[192][1024] bf16 = concat(Wq^T*QSCL, Wk^T, Wv^T) ----
__global__ __launch_bounds__(256) void prep_wt(
    const float* __restrict__ Wq, const float* __restrict__ Wk,
    const float* __restrict__ Wv, bf16* __restrict__ Wt)
{
    __shared__ float Xf[64 * 68];
    const int m = blockIdx.x >> 4, dt = blockIdx.x & 15;
    const float* W = (m == 0) ? Wq : ((m == 1) ? Wk : Wv);
    const int d0 = dt * 64;
#pragma unroll
    for (int j = 0; j < 4; ++j) {
        int i = threadIdx.x + 256 * j;
        int dr = i >> 4, c4 = i & 15;
        float4 v = *(const float4*)(W + (size_t)(d0 + dr) * 64 + c4 * 4);
        *(float4*)&Xf[dr * 68 + c4 * 4] = v;
    }
    __syncthreads();
    const float scl = (m == 0) ? QSCL : 1.0f;
#pragma unroll
    for (int j = 0; j < 4; ++j) {
        int o = threadIdx.x + 256 * j;
        int h = o >> 4, dc = o & 15;
        bf16x4 w;
#pragma unroll
        for (int k = 0; k < 4; ++k) w[k] = (bf16)(Xf[(dc * 4 + k) * 68 + h] * scl);
        *(bf16x4*)(Wt + (size_t)(m * 64 + h) * D + d0 + dc * 4) = w;
    }
}

// ---- fused projection: grid 256 = 8 xcd x 32 mtile; Q+K+V per block ----
__global__ __launch_bounds__(256) void qkv_proj(
    const float* __restrict__ x, const bf16* __restrict__ Wt,
    bf16* __restrict__ Qg, bf16* __restrict__ Kgt, bf16* __restrict__ Vgt)
{
    __shared__ __align__(16) bf16  Xb[2][64 * 64];   // swizzled granule: [r][u^(r&7)]
    __shared__ __align__(16) short Ws[2][192 * 64];  // swizzled: [h][u^(h&7)]
    const int tid = threadIdx.x;
    const int w = tid >> 6, lane = tid & 63, ln5 = lane & 31, hi = lane >> 5;
    const int tt = w & 1, hh = w >> 1;
    const int xcd = blockIdx.x & 7, mlocal = blockIdx.x >> 3;
    const int r0 = (xcd * 32 + mlocal) * 64;
    const int wb = tid & 448;

    auto stageW = [&](int kc, int buf) {
#pragma unroll
        for (int k2 = 0; k2 < 6; ++k2) {
            int s = k2 * 256 + tid;
            int h = s >> 3, j = s & 7, u = j ^ (h & 7);
            gld16(Wt + (size_t)h * D + kc * 64 + u * 8,
                  &Ws[buf][(k2 * 256 + wb) * 8]);
        }
    };
    float4 xra[2], xrb[2];
    auto stageX_load = [&](int kc) {
#pragma unroll
        for (int k = 0; k < 2; ++k) {
            int e = k * 256 + tid;
            int r = e >> 3, d0 = (e & 7) * 8;
            const float* src = x + (size_t)(r0 + r) * D + kc * 64 + d0;
            xra[k] = *(const float4*)src;
            xrb[k] = *(const float4*)(src + 4);
        }
    };
    auto stageX_write = [&](int buf) {
#pragma unroll
        for (int k = 0; k < 2; ++k) {
            int e = k * 256 + tid;
            int r = e >> 3, d0 = (e & 7) * 8;
            bf16x8 v;
            v[0] = (bf16)xra[k].x; v[1] = (bf16)xra[k].y;
            v[2] = (bf16)xra[k].z; v[3] = (bf16)xra[k].w;
            v[4] = (bf16)xrb[k].x; v[5] = (bf16)xrb[k].y;
            v[6] = (bf16)xrb[k].z; v[7] = (bf16)xrb[k].w;
            *(bf16x8*)&Xb[buf][r * 64 + (((d0 >> 3) ^ (r & 7)) * 8)] = v;
        }
    };

    f32x16 acc0 = zero16(), acc1 = zero16(), acc2 = zero16();
    const int rx = tt * 32 + ln5;
    const int hq = hh * 32 + ln5;
    const int swz = ln5 & 7;

    stageX_load(0); stageW(0, 0); stageX_write(0);
    __syncthreads();
    for (int kc = 0; kc < 16; ++kc) {
        const int cur = kc & 1;
        if (kc < 15) { stageW(kc + 1, cur ^ 1); stageX_load(kc + 1); }
        const bf16*  Xc = &Xb[cur][0];
        const short* Wb = &Ws[cur][0];
#pragma unroll
        for (int ks = 0; ks < 4; ++ks) {
            int g = (ks * 2 + hi) ^ swz;
            bf16x8 fx = *(const bf16x8*)&Xc[rx * 64 + g * 8];
            bf16x8 w0 = *(const bf16x8*)&Wb[(hq)       * 64 + g * 8];
            bf16x8 w1 = *(const bf16x8*)&Wb[(64 + hq)  * 64 + g * 8];
            bf16x8 w2 = *(const bf16x8*)&Wb[(128 + hq) * 64 + g * 8];
            acc0 = MFMA(w0, fx, acc0);   // Q: C^T (col = t)
            acc1 = MFMA(w1, fx, acc1);   // K: C^T (col = t)
            acc2 = MFMA(fx, w2, acc2);   // V: C   (col = h)
        }
        if (kc < 15) stageX_write(cur ^ 1);
        __syncthreads();
    }

    {
        int t = r0 + tt * 32 + ln5;
#pragma unroll
        for (int g = 0; g < 4; ++g) {
            int h0 = hh * 32 + 8 * g + 4 * hi;
            bf16x4 v;
#pragma unroll
            for (int k = 0; k < 4; ++k) v[k] = (bf16)acc0[4 * g + k];
            *(bf16x4*)(Qg + (size_t)t * HS + h0) = v;
        }
    }
    {
        int t = r0 + tt * 32 + ln5;
#pragma unroll
        for (int g = 0; g < 4; ++g) {
            int h0 = hh * 32 + 8 * g + 4 * hi;
            bf16x4 v;
#pragma unroll
            for (int k = 0; k < 4; ++k) v[k] = (bf16)acc1[4 * g + k];
            int j = (h0 >> 3) ^ (t & 7);
            *(bf16x4*)(Kgt + (size_t)t * HS + j * 8 + 4 * hi) = v;
        }
    }
    {
        int hr = hh * 32 + ln5;
#pragma unroll
        for (int g = 0; g < 4; ++g) {
            int t0 = tt * 32 + 8 * g + 4 * hi;
            bf16x4 v;
#pragma unroll
            for (int k = 0; k < 4; ++k) v[k] = (bf16)acc2[4 * g + k];
            int j = (t0 >> 3) ^ (hr & 7);
            *(bf16x4*)(Vgt + (size_t)r0 * HS + hr * 64 + j * 8 + 4 * hi) = v;
        }
    }
}

// ---- attention: block = 128 q-rows; wave = 64 q-cols x 32-kr half-chunk ----
// Zero-LDS/zero-barrier k-loop (r15) + T5 setprio around MFMA clusters.
__global__ __launch_bounds__(256, 2) void attn(
    const bf16* __restrict__ Qg, const bf16* __restrict__ Kgt,
    const bf16* __restrict__ Vgt, float* __restrict__ Op,
    float* __restrict__ Lp, float* __restrict__ out, int split)
{
    __shared__ __align__(16) short PO[16384];        // 32 KB: epilogue Ox overlay
    __shared__ float Lx[128];

    const int tid = threadIdx.x;
    const int w = tid >> 6, lane = tid & 63, ln5 = lane & 31, hi = lane >> 5;
    const int wq = w & 1, wk = w >> 1;

    int b, qt, half;
    if (split == 4) {
        int rest = blockIdx.x >> 3; qt = rest & 31;
        int combo = (blockIdx.x & 7) + 8 * (rest >> 5);   // (b,half) pinned per XCD
        b = combo >> 2; half = combo & 3;
    } else if (split == 2) {
        int c2 = blockIdx.x & 7; b = c2 >> 1; half = c2 & 1; qt = blockIdx.x >> 3;
    } else { b = blockIdx.x & 3; half = 0; qt = blockIdx.x >> 2; }

    const int rbase = b * T;
    const int seg = T / split;
    const int kb0 = rbase + half * seg;
    const int nc = seg / 64;
    const int qrow0 = rbase + qt * 128 + wq * 64;

    bf16x8 bq[2][4];
    {
        const bf16* qp = Qg + (size_t)(qrow0 + ln5) * HS + hi * 8;
#pragma unroll
        for (int qs = 0; qs < 2; ++qs)
#pragma unroll
            for (int ks = 0; ks < 4; ++ks)
                bq[qs][ks] = *(const bf16x8*)(qp + (size_t)qs * 32 * HS + ks * 16);
    }

    const bf16* Kc = Kgt + (size_t)kb0 * HS;
    const bf16* Vc = Vgt + (size_t)kb0 * HS;

    f32x16 O00 = zero16(), O01 = zero16(), O10 = zero16(), O11 = zero16();
    float l0 = 0.f, l1 = 0.f;
    const int swz = ln5 & 7;
    const int krow = (wk * 32 + ln5) * 64;           // K frag row (shorts)
    const int ko0 = krow + ((0 + hi) ^ swz) * 8;
    const int ko1 = krow + ((2 + hi) ^ swz) * 8;
    const int ko2 = krow + ((4 + hi) ^ swz) * 8;
    const int ko3 = krow + ((6 + hi) ^ swz) * 8;
    const int ku0 = ((wk * 4 + 0 + hi) ^ swz) * 8;   // PV ks=0
    const int ku1 = ((wk * 4 + 2 + hi) ^ swz) * 8;   // PV ks=1
    const int vr0 = ln5 * 64, vr1 = (32 + ln5) * 64;

    bf16x8 kf0 = *(const bf16x8*)(Kc + ko0);
    bf16x8 kf1 = *(const bf16x8*)(Kc + ko1);
    bf16x8 kf2 = *(const bf16x8*)(Kc + ko2);
    bf16x8 kf3 = *(const bf16x8*)(Kc + ko3);

    union U8 { unsigned u[4]; bf16x8 v; };

    for (int c = 0; c < nc; ++c) {
        const bf16* Vb = Vc + (size_t)c * 4096;
        bf16x8 v00 = *(const bf16x8*)(Vb + vr0 + ku0);
        bf16x8 v01 = *(const bf16x8*)(Vb + vr0 + ku1);
        bf16x8 v10 = *(const bf16x8*)(Vb + vr1 + ku0);
        bf16x8 v11 = *(const bf16x8*)(Vb + vr1 + ku1);
        const bool pf = (c + 1 < nc);
        bf16x8 kn0, kn1, kn2, kn3;
        if (pf) {
            const bf16* Kn = Kc + (size_t)(c + 1) * 4096;
            kn0 = *(const bf16x8*)(Kn + ko0);
            kn1 = *(const bf16x8*)(Kn + ko1);
            kn2 = *(const bf16x8*)(Kn + ko2);
            kn3 = *(const bf16x8*)(Kn + ko3);
        }

        // S^T = K_slice * Q^T  (32 kr x 64 q)  [T5: favor MFMA-issuing wave]
        f32x16 S0 = zero16(), S1 = zero16();
        __builtin_amdgcn_s_setprio(1);
        S0 = MFMA(kf0, bq[0][0], S0); S1 = MFMA(kf0, bq[1][0], S1);
        S0 = MFMA(kf1, bq[0][1], S0); S1 = MFMA(kf1, bq[1][1], S1);
        S0 = MFMA(kf2, bq[0][2], S0); S1 = MFMA(kf2, bq[1][2], S1);
        S0 = MFMA(kf3, bq[0][3], S0); S1 = MFMA(kf3, bq[1][3], S1);
        __builtin_amdgcn_s_setprio(0);

        // no-max softmax; pack P^T to bf16 in-register (T12)
        unsigned wa[8], wbq[8];
#pragma unroll
        for (int g = 0; g < 4; ++g) {
            float p0 = __builtin_amdgcn_exp2f(S0[4 * g + 0]);
            float p1 = __builtin_amdgcn_exp2f(S0[4 * g + 1]);
            float p2 = __builtin_amdgcn_exp2f(S0[4 * g + 2]);
            float p3 = __builtin_amdgcn_exp2f(S0[4 * g + 3]);
            l0 += (p0 + p1) + (p2 + p3);
            asm("v_cvt_pk_bf16_f32 %0, %1, %2" : "=v"(wa[2 * g])     : "v"(p0), "v"(p1));
            asm("v_cvt_pk_bf16_f32 %0, %1, %2" : "=v"(wa[2 * g + 1]) : "v"(p2), "v"(p3));
        }
#pragma unroll
        for (int g = 0; g < 4; ++g) {
            float p0 = __builtin_amdgcn_exp2f(S1[4 * g + 0]);
            float p1 = __builtin_amdgcn_exp2f(S1[4 * g + 1]);
            float p2 = __builtin_amdgcn_exp2f(S1[4 * g + 2]);
            float p3 = __builtin_amdgcn_exp2f(S1[4 * g + 3]);
            l1 += (p0 + p1) + (p2 + p3);
            asm("v_cvt_pk_bf16_f32 %0, %1, %2" : "=v"(wbq[2 * g])     : "v"(p0), "v"(p1));
            asm("v_cvt_pk_bf16_f32 %0, %1, %2" : "=v"(wbq[2 * g + 1]) : "v"(p2), "v"(p3));
        }
#pragma unroll
        for (int j = 0; j < 2; ++j) {
            asm("v_permlane32_swap_b32 %0, %1" : "+v"(wa[j]),      "+v"(wa[j + 2]));
            asm("v_permlane32_swap_b32 %0, %1" : "+v"(wa[4 + j]),  "+v"(wa[6 + j]));
            asm("v_permlane32_swap_b32 %0, %1" : "+v"(wbq[j]),     "+v"(wbq[j + 2]));
            asm("v_permlane32_swap_b32 %0, %1" : "+v"(wbq[4 + j]), "+v"(wbq[6 + j]));
        }
        U8 fa0, fa1, fb0, fb1;
        fa0.u[0] = wa[0];  fa0.u[1] = wa[1];  fa0.u[2] = wa[2];  fa0.u[3] = wa[3];
        fa1.u[0] = wa[4];  fa1.u[1] = wa[5];  fa1.u[2] = wa[6];  fa1.u[3] = wa[7];
        fb0.u[0] = wbq[0]; fb0.u[1] = wbq[1]; fb0.u[2] = wbq[2]; fb0.u[3] = wbq[3];
        fb1.u[0] = wbq[4]; fb1.u[1] = wbq[5]; fb1.u[2] = wbq[6]; fb1.u[3] = wbq[7];

        // O^T += V^T_slice * P^T  [T5]
        __builtin_amdgcn_s_setprio(1);
        O00 = MFMA(v00, fa0.v, O00);
        O01 = MFMA(v00, fb0.v, O01);
        O10 = MFMA(v10, fa0.v, O10);
        O11 = MFMA(v10, fb0.v, O11);
        O00 = MFMA(v01, fa1.v, O00);
        O01 = MFMA(v01, fb1.v, O01);
        O10 = MFMA(v11, fa1.v, O10);
        O11 = MFMA(v11, fb1.v, O11);
        __builtin_amdgcn_s_setprio(0);

        if (pf) { kf0 = kn0; kf1 = kn1; kf2 = kn2; kf3 = kn3; }
    }

    l0 += __shfl_xor(l0, 32, 64);
    l1 += __shfl_xor(l1, 32, 64);

    // wk-combine through the 32 KB Ox overlay
    __syncthreads();
    float* Ox = (float*)&PO[0];                      // [wq][h 64][q 64]
    if (wk == 1) {
#pragma unroll
        for (int g = 0; g < 4; ++g)
#pragma unroll
            for (int k = 0; k < 4; ++k) {
                int h0 = 8 * g + 4 * hi + k;
                Ox[wq * 4096 + h0 * 64 + ln5]             = O00[4 * g + k];
                Ox[wq * 4096 + h0 * 64 + 32 + ln5]        = O01[4 * g + k];
                Ox[wq * 4096 + (32 + h0) * 64 + ln5]      = O10[4 * g + k];
                Ox[wq * 4096 + (32 + h0) * 64 + 32 + ln5] = O11[4 * g + k];
            }
        if (hi == 0) { Lx[wq * 64 + ln5] = l0; Lx[wq * 64 + 32 + ln5] = l1; }
    }
    __syncthreads();
    if (wk == 0) {
#pragma unroll
        for (int g = 0; g < 4; ++g)
#pragma unroll
            for (int k = 0; k < 4; ++k) {
                int h0 = 8 * g + 4 * hi + k;
                O00[4 * g + k] += Ox[wq * 4096 + h0 * 64 + ln5];
                O01[4 * g + k] += Ox[wq * 4096 + h0 * 64 + 32 + ln5];
                O10[4 * g + k] += Ox[wq * 4096 + (32 + h0) * 64 + ln5];
                O11[4 * g + k] += Ox[wq * 4096 + (32 + h0) * 64 + 32 + ln5];
            }
        l0 += Lx[wq * 64 + ln5];
        l1 += Lx[wq * 64 + 32 + ln5];

        int q0 = qrow0 + ln5, q1 = qrow0 + 32 + ln5;
        if (split == 1) {
            float i0 = 1.0f / l0, i1 = 1.0f / l1;
#pragma unroll
            for (int g = 0; g < 4; ++g) {
                int h0 = 8 * g + 4 * hi;
                float4 o;
                o.x = O00[4*g+0]*i0; o.y = O00[4*g+1]*i0; o.z = O00[4*g+2]*i0; o.w = O00[4*g+3]*i0;
                *(float4*)(out + (size_t)q0 * HS + h0) = o;
                o.x = O01[4*g+0]*i1; o.y = O01[4*g+1]*i1; o.z = O01[4*g+2]*i1; o.w = O01[4*g+3]*i1;
                *(float4*)(out + (size_t)q1 * HS + h0) = o;
                o.x = O10[4*g+0]*i0; o.y = O10[4*g+1]*i0; o.z = O10[4*g+2]*i0; o.w = O10[4*g+3]*i0;
                *(float4*)(out + (size_t)q0 * HS + 32 + h0) = o;
                o.x = O11[4*g+0]*i1; o.y = O11[4*g+1]*i1; o.z = O11[4*g+2]*i1; o.w = O11[4*g+3]*i1;
                *(float4*)(out + (size_t)q1 * HS + 32 + h0) = o;
            }
        } else {
            float* Od = Op + (size_t)half * ROWS * HS;
#pragma unroll
            for (int g = 0; g < 4; ++g) {
                int h0 = 8 * g + 4 * hi;
                float4 o;
                o.x = O00[4*g+0]; o.y = O00[4*g+1]; o.z = O00[4*g+2]; o.w = O00[4*g+3];
                *(float4*)(Od + (size_t)q0 * HS + h0) = o;
                o.x = O01[4*g+0]; o.y = O01[4*g+1]; o.z = O01[4*g+2]; o.w = O01[4*g+3];
                *(float4*)(Od + (size_t)q1 * HS + h0) = o;
                o.x = O10[4*g+0]; o.y = O10[4*g+1]; o.z = O10[4*g+2]; o.w = O10[4*g+3];
                *(float4*)(Od + (size_t)q0 * HS + 32 + h0) = o;
                o.x = O11[4*g+0]; o.y = O11[4*g+1]; o.z = O11[4*g+2]; o.w = O11[4*g+3];
                *(float4*)(Od + (size_t)q1 * HS + 32 + h0) = o;
            }
            if (hi == 0) {
                Lp[half * ROWS + q0] = l0;
                Lp[half * ROWS + q1] = l1;
            }
        }
    }
}

// ---- reduce: out = sum_h(O_h) / sum_h(l_h) ----
__global__ __launch_bounds__(256) void attn_reduce(
    const float* __restrict__ Op, const float* __restrict__ Lp,
    float* __restrict__ out, int split)
{
    int idx = blockIdx.x * 256 + threadIdx.x;        // float4 index
    int row = idx >> 4;
    float4 s; s.x = s.y = s.z = s.w = 0.f;
    float lsum = 0.f;
    for (int h = 0; h < split; ++h) {
        float4 a = *(const float4*)(Op + (size_t)h * ROWS * HS + (size_t)idx * 4);
        s.x += a.x; s.y += a.y; s.z += a.z; s.w += a.w;
        lsum += Lp[h * ROWS + row];
    }
    float inv = 1.0f / lsum;
    s.x *= inv; s.y *= inv; s.z *= inv; s.w *= inv;
    *(float4*)(out + (size_t)idx * 4) = s;
}

extern "C" void kernel_launch(void* const* d_in, const int* in_sizes, int n_in,
                              void* d_out, int out_size, void* d_ws, size_t ws_size,
                              hipStream_t stream)
{
    const float* x  = (const float*)d_in[0];
    const float* Wq = (const float*)d_in[1];
    const float* Wk = (const float*)d_in[2];
    const float* Wv = (const float*)d_in[3];
    float* out = (float*)d_out;

    char* ws = (char*)d_ws;
    bf16* Qg  = (bf16*)(ws);                          // 2 MB  [16384][64]
    bf16* Kgt = (bf16*)(ws + ((size_t)2 << 20));      // 2 MB  tiled+swizzled
    bf16* Vgt = (bf16*)(ws + ((size_t)4 << 20));      // 2 MB  tiled+swizzled
    bf16* Wt  = (bf16*)(ws + ((size_t)6 << 20));      // 384 KB [192][1024]
    float* Lp = (float*)(ws + ((size_t)6 << 20));     // overlays Wt (dead after proj)
    float* Op = (float*)(ws + ((size_t)6 << 20) + ((size_t)1 << 19));

    const size_t base = ((size_t)6 << 20) + ((size_t)1 << 19);
    int split = 1;
    if (ws_size >= base + (size_t)4 * ROWS * HS * sizeof(float)) split = 4;
    else if (ws_size >= base + (size_t)2 * ROWS * HS * sizeof(float)) split = 2;

    prep_wt<<<48, 256, 0, stream>>>(Wq, Wk, Wv, Wt);
    qkv_proj<<<256, 256, 0, stream>>>(x, Wt, Qg, Kgt, Vgt);
    attn<<<128 * split, 256, 0, stream>>>(Qg, Kgt, Vgt, Op, Lp, out, split);
    if (split > 1)
        attn_reduce<<<(ROWS * HS / 4) / 256, 256, 0, stream>>>(Op, Lp, out, split);
}